// Round 7
// baseline (5511.684 us; speedup 1.0000x reference)
//
#include <hip/hip_runtime.h>
#include <hip/hip_fp16.h>
#include <math.h>

#define NUSERS 100000
#define NITEMS 50000
#define BATCH  64
#define ORDER  8
#define BSHIFT 9                                   // 512 rows per bucket
#define BROWS  (1 << BSHIFT)
#define NBUCKU ((NUSERS + BROWS - 1) >> BSHIFT)    // 196
#define NBUCKI ((NITEMS + BROWS - 1) >> BSHIFT)    // 98
#define CAPU 16384
#define CAPI 24576
#define S1_BLOCKS 512
#define NREP 4
#define GRID_BLOCKS 1024                           // 4 blocks/CU x 256 CUs
#define NSTRIPE 16

// ---------------------------------------------------------------------------
// R23: R22 failed the graph-capture tripwire -- hipLaunchCooperativeKernel is
// not capturable, so the graph recorded the fallback while launch_once ran
// the coop kernel (which also had a pad-clobber bug from stU aliasing
// tauHall with pad-zeroing moved before scatter1). Fixes: (a) plain launch
// of ONE persistent kernel, 1024 blocks @ __launch_bounds__(256,4) -> 4
// blocks/CU co-resident by construction; (b) software grid barrier (16
// striped arrival counters -> root -> release flag, agent-scope atomics,
// s_sleep spin, threadfence both sides -- same mechanism as ockl_grid_sync);
// (c) stU/stI carved separately (no aliasing; ~142MB < 256MB ws); (d) zero
// code-path branching. Phase math identical to verified R19. The R21-derived
// ~17us/dispatch boundary-overhead theory stands: 23 dispatches -> 2.
// Predicted: mono kernel 450-550us, total 755 -> ~480-580us.
// Failure reads: timeout = residency broken; >=700us = overhead theory wrong.
// ---------------------------------------------------------------------------

struct __align__(8) Half4 { __half2 a, b; };
struct Coeffs { float v[ORDER + 1]; };

#define SLOT ((size_t)(NITEMS + 1) * BATCH)        // fp16 tau slot incl. zero row

__device__ __forceinline__ void acc_pk(float4& acc, Half4 v0, Half4 v1,
                                       Half4 v2, Half4 v3) {
    __half2 sa = __hadd2(__hadd2(v0.a, v1.a), __hadd2(v2.a, v3.a));
    __half2 sb = __hadd2(__hadd2(v0.b, v1.b), __hadd2(v2.b, v3.b));
    float2 fa = __half22float2(sa);
    float2 fb = __half22float2(sb);
    acc.x += fa.x; acc.y += fa.y; acc.z += fb.x; acc.w += fb.y;
}

__device__ __forceinline__ Half4 to_h4(float x, float y, float z, float w) {
    Half4 h;
    h.a = __floats2half2_rn(x, y);
    h.b = __floats2half2_rn(z, w);
    return h;
}

// ---------------------------------------------------------------------------
// Software grid barrier. bar layout (u32): [0..255] 16 stripes (stride 16),
// [256] root, [272] flag. Monotonic phase, zeroed via hipMemsetAsync each
// launch. All 1024 blocks co-resident (launch_bounds) -> no deadlock.
// ---------------------------------------------------------------------------
__device__ __forceinline__ void gbar(unsigned* bar, unsigned phase) {
    __syncthreads();
    if (threadIdx.x == 0) {
        __threadfence();                                        // release
        unsigned* stripe = bar + ((blockIdx.x & (NSTRIPE - 1)) << 4);
        unsigned prev = __hip_atomic_fetch_add(stripe, 1u, __ATOMIC_ACQ_REL,
                                               __HIP_MEMORY_SCOPE_AGENT);
        if (prev + 1 == (GRID_BLOCKS / NSTRIPE) * phase) {
            unsigned r = __hip_atomic_fetch_add(bar + 256, 1u, __ATOMIC_ACQ_REL,
                                                __HIP_MEMORY_SCOPE_AGENT);
            if (r + 1 == NSTRIPE * phase)
                __hip_atomic_store(bar + 272, phase, __ATOMIC_RELEASE,
                                   __HIP_MEMORY_SCOPE_AGENT);
        }
        while (__hip_atomic_load(bar + 272, __ATOMIC_ACQUIRE,
                                 __HIP_MEMORY_SCOPE_AGENT) < phase)
            __builtin_amdgcn_s_sleep(1);
        __threadfence();                                        // acquire
    }
    __syncthreads();
}

// ---------------------------------------------------------------------------
// R19 gather core (verified): int4 idx loads + 32-bit byte offsets.
// ---------------------------------------------------------------------------
__device__ __forceinline__ void gather4_p(const int* __restrict__ idx,
                                          const Half4* __restrict__ x,
                                          const int* b, const int* n,
                                          int sub, int bh, float4* a) {
    const char* __restrict__ xb = (const char*)x;
    const char* __restrict__ ib = (const char*)idx;
    const unsigned bhoff = (unsigned)bh << 3;
    unsigned jb[4];
    int nmax = 0;
    #pragma unroll
    for (int q = 0; q < 4; ++q) {
        jb[q] = ((unsigned)b[q] << 2) + ((unsigned)sub << 4);
        nmax = max(nmax, n[q]);
    }
    for (int it = 0; it < nmax; ++it) {
        #pragma unroll
        for (int q = 0; q < 4; ++q) {
            if (it < n[q]) {
                int4 ii = *(const int4*)(ib + jb[q]);
                Half4 v0 = *(const Half4*)(xb + (((unsigned)ii.x << 7) + bhoff));
                Half4 v1 = *(const Half4*)(xb + (((unsigned)ii.y << 7) + bhoff));
                Half4 v2 = *(const Half4*)(xb + (((unsigned)ii.z << 7) + bhoff));
                Half4 v3 = *(const Half4*)(xb + (((unsigned)ii.w << 7) + bhoff));
                acc_pk(a[q], v0, v1, v2, v3);
                jb[q] += 64;
            }
        }
    }
    #pragma unroll
    for (int q = 0; q < 4; ++q) {
        a[q].x += __shfl_xor(a[q].x, 16); a[q].y += __shfl_xor(a[q].y, 16);
        a[q].z += __shfl_xor(a[q].z, 16); a[q].w += __shfl_xor(a[q].w, 16);
        a[q].x += __shfl_xor(a[q].x, 32); a[q].y += __shfl_xor(a[q].y, 32);
        a[q].z += __shfl_xor(a[q].z, 32); a[q].w += __shfl_xor(a[q].w, 32);
    }
}

__device__ __forceinline__ void user_quad(int w, int lane,
                                          const int* __restrict__ ptr,
                                          const int* __restrict__ deg,
                                          const int* __restrict__ idx,
                                          const Half4* __restrict__ tauH,
                                          Half4* __restrict__ y) {
    const int H = NUSERS / 4;
    int r[4] = {w, w + H, w + 2 * H, w + 3 * H};
    const int sub = lane >> 4;
    const int bh  = lane & 15;
    int b[4], d[4], n[4];
    #pragma unroll
    for (int q = 0; q < 4; ++q) {
        b[q] = ptr[r[q]];
        d[q] = deg[r[q]];
        n[q] = (d[q] + 15) >> 4;
    }
    float4 a[4] = {{0,0,0,0},{0,0,0,0},{0,0,0,0},{0,0,0,0}};
    gather4_p(idx, tauH, b, n, sub, bh, a);
    if (sub == 0) {
        #pragma unroll
        for (int q = 0; q < 4; ++q) {
            float s = (d[q] > 0) ? 1.0f / (float)d[q] : 0.0f;
            y[(size_t)r[q] * 16 + bh] = to_h4(s * a[q].x, s * a[q].y, s * a[q].z, s * a[q].w);
        }
    }
}

__device__ __forceinline__ void item_first_quad(int w, int lane,
                                                const int* __restrict__ ptr,
                                                const int* __restrict__ deg,
                                                const int* __restrict__ idx,
                                                const Half4* __restrict__ y,
                                                const float* __restrict__ tau0,
                                                float* __restrict__ tau1,
                                                Half4* __restrict__ tauH1) {
    const int H = NITEMS / 4;
    int r[4] = {w, w + H, w + 2 * H, w + 3 * H};
    const int sub = lane >> 4;
    const int bh  = lane & 15;
    int b[4], d[4], n[4];
    #pragma unroll
    for (int q = 0; q < 4; ++q) {
        b[q] = ptr[r[q]];
        d[q] = deg[r[q]];
        n[q] = (d[q] + 15) >> 4;
    }
    float4 a[4] = {{0,0,0,0},{0,0,0,0},{0,0,0,0},{0,0,0,0}};
    gather4_p(idx, y, b, n, sub, bh, a);
    if (sub == 0) {
        #pragma unroll
        for (int q = 0; q < 4; ++q) {
            float inv = (d[q] > 0) ? 1.0f / (float)d[q] : 0.0f;
            float s2 = 2.0f * inv;
            size_t base = (size_t)r[q] * BATCH + (bh << 2);
            float4 t0v = *(const float4*)&tau0[base];
            float4 t;
            t.x = t0v.x - s2 * a[q].x; t.y = t0v.y - s2 * a[q].y;
            t.z = t0v.z - s2 * a[q].z; t.w = t0v.w - s2 * a[q].w;
            *(float4*)&tau1[base] = t;
            tauH1[(size_t)r[q] * 16 + bh] = to_h4(t.x, t.y, t.z, t.w);
        }
    }
}

__device__ __forceinline__ void item_k_quad(int w, int lane,
                                            const int* __restrict__ ptr,
                                            const int* __restrict__ deg,
                                            const int* __restrict__ idx,
                                            const Half4* __restrict__ y,
                                            const float* __restrict__ tau1,
                                            float* __restrict__ tau0,
                                            Half4* __restrict__ tauHk) {
    const int H = NITEMS / 4;
    int r[4] = {w, w + H, w + 2 * H, w + 3 * H};
    const int sub = lane >> 4;
    const int bh  = lane & 15;
    int b[4], d[4], n[4];
    #pragma unroll
    for (int q = 0; q < 4; ++q) {
        b[q] = ptr[r[q]];
        d[q] = deg[r[q]];
        n[q] = (d[q] + 15) >> 4;
    }
    float4 a[4] = {{0,0,0,0},{0,0,0,0},{0,0,0,0},{0,0,0,0}};
    gather4_p(idx, y, b, n, sub, bh, a);
    if (sub == 0) {
        #pragma unroll
        for (int q = 0; q < 4; ++q) {
            float inv = (d[q] > 0) ? 1.0f / (float)d[q] : 0.0f;
            float s4 = 4.0f * inv;
            size_t base = (size_t)r[q] * BATCH + (bh << 2);
            float4 t1v = *(const float4*)&tau1[base];
            float4 t0v = *(const float4*)&tau0[base];
            float4 t2;
            t2.x = 2.0f * t1v.x - s4 * a[q].x - t0v.x;
            t2.y = 2.0f * t1v.y - s4 * a[q].y - t0v.y;
            t2.z = 2.0f * t1v.z - s4 * a[q].z - t0v.z;
            t2.w = 2.0f * t1v.w - s4 * a[q].w - t0v.w;
            *(float4*)&tau0[base] = t2;
            tauHk[(size_t)r[q] * 16 + bh] = to_h4(t2.x, t2.y, t2.z, t2.w);
        }
    }
}

__device__ __forceinline__ void tscale_item(int c, const float* __restrict__ signal,
                                            const int* __restrict__ ideg,
                                            float* __restrict__ tauA,
                                            __half* __restrict__ tauH0) {
    int d = ideg[c];
    float dis = (d > 0) ? rsqrtf((float)d) : 0.0f;
    #pragma unroll
    for (int g = 0; g < 4; ++g) {
        float v[16];
        #pragma unroll
        for (int r = 0; r < 16; ++r)
            v[r] = dis * signal[(size_t)(g * 16 + r) * NITEMS + c];
        #pragma unroll
        for (int r = 0; r < 16; r += 4)
            *(float4*)&tauA[(size_t)c * BATCH + g * 16 + r] =
                make_float4(v[r], v[r+1], v[r+2], v[r+3]);
        union { __half2 h2[8]; uint4 u4[2]; } pk;
        #pragma unroll
        for (int j = 0; j < 8; ++j) pk.h2[j] = __floats2half2_rn(v[2*j], v[2*j+1]);
        uint4* dst = (uint4*)&tauH0[(size_t)c * BATCH + g * 16];
        dst[0] = pk.u4[0];
        dst[1] = pk.u4[1];
    }
}

__device__ __forceinline__ void tout_item(int c, const __half* __restrict__ tauH,
                                          const float* __restrict__ signal,
                                          const int* __restrict__ ideg,
                                          float csum, const Coeffs& cf,
                                          float* __restrict__ out) {
    int d = ideg[c];
    if (d > 0) {
        float sc = sqrtf((float)d);
        #pragma unroll
        for (int g = 0; g < 4; ++g) {
            float s[16];
            #pragma unroll
            for (int r = 0; r < 16; ++r) s[r] = 0.f;
            for (int k = 0; k <= ORDER; ++k) {
                union { uint4 u4[2]; __half2 h2[8]; } pk;
                const uint4* src =
                    (const uint4*)&tauH[(size_t)k * SLOT + (size_t)c * BATCH + g * 16];
                pk.u4[0] = src[0];
                pk.u4[1] = src[1];
                float ck = cf.v[k];
                #pragma unroll
                for (int j = 0; j < 8; ++j) {
                    float2 f = __half22float2(pk.h2[j]);
                    s[2*j]     += ck * f.x;
                    s[2*j + 1] += ck * f.y;
                }
            }
            #pragma unroll
            for (int r = 0; r < 16; ++r)
                out[(size_t)(g * 16 + r) * NITEMS + c] = sc * s[r];
        }
    } else {
        for (int r = 0; r < BATCH; ++r)
            out[(size_t)r * NITEMS + c] = csum * signal[(size_t)r * NITEMS + c];
    }
}

__device__ void scatter1_body(int blk, const int* __restrict__ row,
                              const int* __restrict__ col,
                              int* __restrict__ bcurU, int* __restrict__ bcurI,
                              int* __restrict__ stU, int* __restrict__ stI,
                              int nnz, int* sm) {
    int* cU = sm;
    int* cI = sm + NREP * NBUCKU;
    const int tid = threadIdx.x;
    const int chunk = (nnz + S1_BLOCKS - 1) / S1_BLOCKS;
    const int b0 = blk * chunk;
    const int e0 = min(b0 + chunk, nnz);
    const int sw = tid >> 6;
    for (int t = tid; t < NREP * NBUCKU; t += 256) cU[t] = 0;
    for (int t = tid; t < NREP * NBUCKI; t += 256) cI[t] = 0;
    __syncthreads();
    for (int i = b0 + tid; i < e0; i += 256) {
        atomicAdd(&cU[sw * NBUCKU + (row[i] >> BSHIFT)], 1);
        atomicAdd(&cI[sw * NBUCKI + (col[i] >> BSHIFT)], 1);
    }
    __syncthreads();
    for (int t = tid; t < NBUCKU; t += 256) {
        int c0 = cU[t], c1 = cU[NBUCKU + t], c2 = cU[2*NBUCKU + t], c3 = cU[3*NBUCKU + t];
        int tot = c0 + c1 + c2 + c3;
        int base = (tot > 0) ? atomicAdd(&bcurU[t], tot) : 0;
        cU[t] = base;
        cU[NBUCKU + t] = base + c0;
        cU[2*NBUCKU + t] = base + c0 + c1;
        cU[3*NBUCKU + t] = base + c0 + c1 + c2;
    }
    for (int t = tid; t < NBUCKI; t += 256) {
        int c0 = cI[t], c1 = cI[NBUCKI + t], c2 = cI[2*NBUCKI + t], c3 = cI[3*NBUCKI + t];
        int tot = c0 + c1 + c2 + c3;
        int base = (tot > 0) ? atomicAdd(&bcurI[t], tot) : 0;
        cI[t] = base;
        cI[NBUCKI + t] = base + c0;
        cI[2*NBUCKI + t] = base + c0 + c1;
        cI[3*NBUCKI + t] = base + c0 + c1 + c2;
    }
    __syncthreads();
    for (int i = b0 + tid; i < e0; i += 256) {
        int r = row[i], c = col[i];
        int pu = atomicAdd(&cU[sw * NBUCKU + (r >> BSHIFT)], 1);
        stU[pu] = ((r & (BROWS - 1)) << 17) | c;
        int pi = atomicAdd(&cI[sw * NBUCKI + (c >> BSHIFT)], 1);
        stI[pi] = ((c & (BROWS - 1)) << 17) | r;
    }
}

__device__ void scatter2_body(int bucket, const int* __restrict__ bcur,
                              const int* __restrict__ st, int* __restrict__ ptr,
                              int* __restrict__ degOut, int* __restrict__ outIdx,
                              int nrows, int cap, int dummyIdx, int* sm) {
    int* deg = sm;
    int* ps  = sm + BROWS;
    int* cur = sm + BROWS + 256;
    int* rs  = sm + 2 * BROWS + 256;
    const int rbase = bucket << BSHIFT;
    const int nr = min(BROWS, nrows - rbase);
    const int lo = bucket * cap;
    const int hi = bcur[bucket];
    const int t = threadIdx.x;
    deg[2 * t] = 0;
    deg[2 * t + 1] = 0;
    __syncthreads();
    for (int j = lo + t; j < hi; j += 256)
        atomicAdd(&deg[st[j] >> 17], 1);
    __syncthreads();
    int a = deg[2 * t];
    int b = deg[2 * t + 1];
    int pa = (a + 15) & ~15;
    int pb = (b + 15) & ~15;
    ps[t] = pa + pb;
    __syncthreads();
    for (int off = 1; off < 256; off <<= 1) {
        int u = (t >= off) ? ps[t - off] : 0;
        __syncthreads();
        ps[t] += u;
        __syncthreads();
    }
    int excl = (t > 0) ? ps[t - 1] : 0;
    int p0 = lo + excl;
    int p1 = p0 + pa;
    rs[2 * t] = p0;
    rs[2 * t + 1] = p1;
    cur[2 * t] = p0;
    cur[2 * t + 1] = p1;
    if (2 * t < nr)     { ptr[rbase + 2 * t] = p0;     degOut[rbase + 2 * t] = a; }
    if (2 * t + 1 < nr) { ptr[rbase + 2 * t + 1] = p1; degOut[rbase + 2 * t + 1] = b; }
    __syncthreads();
    for (int j = lo + t; j < hi; j += 256) {
        int v = st[j];
        int p = atomicAdd(&cur[v >> 17], 1);
        outIdx[p] = v & 0x1FFFF;
    }
    __syncthreads();
    for (int i = t; i < nr; i += 256) {
        int endReal = cur[i];
        int endPad  = rs[i] + ((deg[i] + 15) & ~15);
        for (int j = endReal; j < endPad; ++j) outIdx[j] = dummyIdx;
    }
}

// ---------------------------------------------------------------------------
// THE kernel: whole pipeline, one plain dispatch, software grid barriers.
// ---------------------------------------------------------------------------
struct ChebyParams {
    const float* signal; const int* row; const int* col; int nnz;
    float* out;
    float* tauA; float* tauB; __half* tauH; Half4* ybuf;
    int* uptr; int* iptr; int* udeg; int* ideg;
    int* bcurU; int* bcurI; int* ucol; int* irow; int* stU; int* stI;
    unsigned* bar;
    Coeffs cf; float csum;
};

__global__ void __launch_bounds__(256, 4) cheby_mono(ChebyParams p) {
    __shared__ int smem[1792];
    unsigned ph = 0;
    const int tid = threadIdx.x;
    const int gtid = blockIdx.x * 256 + tid;
    const int nthr = GRID_BLOCKS * 256;
    const int lane = tid & 63;
    const int wid = gtid >> 6;
    const int TW = nthr >> 6;

    // P0: init reservations + zero pad rows (stU/stI do NOT alias tauH now)
    if (gtid < NBUCKU) p.bcurU[gtid] = gtid * CAPU;
    if (gtid < NBUCKI) p.bcurI[gtid] = gtid * CAPI;
    if (gtid < BATCH) {
        for (int k = 0; k <= ORDER; ++k)
            p.tauH[(size_t)k * SLOT + (size_t)NITEMS * BATCH + gtid] = __float2half(0.f);
        ((__half*)p.ybuf)[(size_t)NUSERS * BATCH + gtid] = __float2half(0.f);
    }
    gbar(p.bar, ++ph);

    // P1: scatter1 on 512 blocks (proven atomic-chain length)
    if (blockIdx.x < S1_BLOCKS)
        scatter1_body(blockIdx.x, p.row, p.col, p.bcurU, p.bcurI, p.stU, p.stI,
                      p.nnz, smem);
    gbar(p.bar, ++ph);

    // P2: scatter2 U and I concurrently
    if (blockIdx.x < NBUCKU)
        scatter2_body(blockIdx.x, p.bcurU, p.stU, p.uptr, p.udeg, p.ucol,
                      NUSERS, CAPU, NITEMS, smem);
    else if (blockIdx.x < NBUCKU + NBUCKI)
        scatter2_body(blockIdx.x - NBUCKU, p.bcurI, p.stI, p.iptr, p.ideg, p.irow,
                      NITEMS, CAPI, NUSERS, smem);
    gbar(p.bar, ++ph);

    // P3: tau0 = D^-1/2 signal^T (fp32 + fp16 slot 0)
    for (int c = gtid; c < NITEMS; c += nthr)
        tscale_item(c, p.signal, p.ideg, p.tauA, p.tauH);
    gbar(p.bar, ++ph);

    // P4..: 8 Chebyshev steps
    float* t0 = p.tauA;
    float* t1 = p.tauB;
    for (int k = 1; k <= ORDER; ++k) {
        const Half4* tin = (const Half4*)(p.tauH + (size_t)(k - 1) * SLOT);
        for (int w = wid; w < NUSERS / 4; w += TW)
            user_quad(w, lane, p.uptr, p.udeg, p.ucol, tin, p.ybuf);
        gbar(p.bar, ++ph);
        Half4* tout = (Half4*)(p.tauH + (size_t)k * SLOT);
        if (k == 1) {
            for (int w = wid; w < NITEMS / 4; w += TW)
                item_first_quad(w, lane, p.iptr, p.ideg, p.irow, p.ybuf, t0, t1, tout);
        } else {
            for (int w = wid; w < NITEMS / 4; w += TW)
                item_k_quad(w, lane, p.iptr, p.ideg, p.irow, p.ybuf, t1, t0, tout);
            float* tmp = t0; t0 = t1; t1 = tmp;
        }
        gbar(p.bar, ++ph);
    }

    // P_last: out = sqrt(di) * sum_k c_k tauH_k (transposed)
    for (int c = gtid; c < NITEMS; c += nthr)
        tout_item(c, p.tauH, p.signal, p.ideg, p.csum, p.cf, p.out);
}

// ---------------------------------------------------------------------------
// Host-side exact replica of reference cheby_coeffs
// ---------------------------------------------------------------------------
static void cheby_coeffs_host(float* c) {
    const int order = ORDER, flatness = 2;
    const double PI = 3.14159265358979323846;
    double tgt[ORDER + 1], nodes[ORDER + 1];
    for (int x = 0; x <= order; ++x) {
        double xv = cos((double)(order - x) / order * PI);
        xv = nearbyint(xv * 1000.0) / 1000.0;
        double t = (xv < 0.0) ? pow(-xv, (double)flatness) * 0.5 + 0.5
                              : pow(xv, (double)flatness) * (-0.5) + 0.5;
        tgt[x] = nearbyint(t * 1000.0) / 1000.0;
    }
    for (int k = 1; k <= order + 1; ++k)
        nodes[k - 1] = cos((order + 1 + 0.5 - k) / (double)(order + 1) * PI);

    double prev[ORDER + 1], cur[ORDER + 1], nxt[ORDER + 1];
    double sums[ORDER + 1];
    double s0 = 0, s1 = 0;
    for (int i = 0; i <= order; ++i) {
        prev[i] = tgt[i];
        cur[i]  = nodes[i] * tgt[i];
        s0 += prev[i];
        s1 += cur[i];
    }
    sums[0] = s0; sums[1] = s1;
    for (int j = 2; j <= order; ++j) {
        double s = 0;
        for (int i = 0; i <= order; ++i) {
            nxt[i] = nodes[i] * cur[i] * 2.0 - prev[i];
            s += nxt[i];
        }
        sums[j] = s;
        for (int i = 0; i <= order; ++i) { prev[i] = cur[i]; cur[i] = nxt[i]; }
    }
    for (int j = 0; j <= order; ++j)
        c[j] = (float)(sums[j] * (2.0 / (order + 1)));
    c[0] *= 0.5f;
}

extern "C" void kernel_launch(void* const* d_in, const int* in_sizes, int n_in,
                              void* d_out, int out_size, void* d_ws, size_t ws_size,
                              hipStream_t stream) {
    const float* signal = (const float*)d_in[0];   // [BATCH, NITEMS]
    const int*   row    = (const int*)d_in[2];     // [NNZ] -> users
    const int*   col    = (const int*)d_in[3];     // [NNZ] -> items
    const int nnz = in_sizes[1];

    char* wsb = (char*)d_ws;
    size_t off = 0;
    auto carve = [&](size_t nbytes) {
        void* p = wsb + off;
        off += (nbytes + 255) & ~(size_t)255;
        return p;
    };
    const size_t NB = (size_t)NITEMS * BATCH;
    const size_t NEU = (size_t)NBUCKU * CAPU;
    const size_t NEI = (size_t)NBUCKI * CAPI;
    float*    tauA   = (float*)carve(NB * 4);
    float*    tauB   = (float*)carve(NB * 4);
    __half*   tauHall = (__half*)carve((ORDER + 1) * SLOT * 2);
    Half4*    ybuf   = (Half4*)carve(((size_t)NUSERS + 1) * BATCH * 2);
    int*      uptr   = (int*)carve(NUSERS * 4);
    int*      iptr   = (int*)carve(NITEMS * 4);
    int*      udeg   = (int*)carve(NUSERS * 4);
    int*      ideg   = (int*)carve(NITEMS * 4);
    int*      bcurU  = (int*)carve(NBUCKU * 4);
    int*      bcurI  = (int*)carve(NBUCKI * 4);
    int*      ucol   = (int*)carve(NEU * 4);
    int*      irow   = (int*)carve(NEI * 4);
    int*      stU    = (int*)carve(NEU * 4);     // separate carve: no aliasing
    int*      stI    = (int*)carve(NEI * 4);
    unsigned* bar    = (unsigned*)carve(2048);
    (void)ws_size;

    float c[ORDER + 1];
    cheby_coeffs_host(c);
    Coeffs cf;
    float csum = 0.f;
    for (int k = 0; k <= ORDER; ++k) { cf.v[k] = c[k]; csum += c[k]; }

    ChebyParams prm;
    prm.signal = signal; prm.row = row; prm.col = col; prm.nnz = nnz;
    prm.out = (float*)d_out;
    prm.tauA = tauA; prm.tauB = tauB; prm.tauH = tauHall; prm.ybuf = ybuf;
    prm.uptr = uptr; prm.iptr = iptr; prm.udeg = udeg; prm.ideg = ideg;
    prm.bcurU = bcurU; prm.bcurI = bcurI; prm.ucol = ucol; prm.irow = irow;
    prm.stU = stU; prm.stI = stI;
    prm.bar = bar;
    prm.cf = cf; prm.csum = csum;

    hipMemsetAsync(bar, 0, 2048, stream);
    cheby_mono<<<GRID_BLOCKS, 256, 0, stream>>>(prm);
}

// Round 8
// 726.187 us; speedup vs baseline: 7.5899x; 7.5899x over previous
//
#include <hip/hip_runtime.h>
#include <hip/hip_fp16.h>
#include <math.h>

#define NUSERS 100000
#define NITEMS 50000
#define BATCH  64
#define ORDER  8
#define BSHIFT 9                                   // 512 rows per bucket
#define BROWS  (1 << BSHIFT)
#define NBUCKU ((NUSERS + BROWS - 1) >> BSHIFT)    // 196
#define NBUCKI ((NITEMS + BROWS - 1) >> BSHIFT)    // 98
#define CAPU 16384
#define CAPI 24576
#define S1_BLOCKS 512
#define S1_THREADS 1024
#define NREP 8
#define S1_SW(t) (((t) >> 6) & (NREP - 1))

// ---------------------------------------------------------------------------
// R24: R23 mono kernel = 5512us, VALU 3.5% / HBM 4% -> idle-dominated. The
// software grid barrier's device-scope fences invalidate per-XCD L2 every
// phase (FETCH 1.78GB), TLP was halved, and static partitions add tails.
// The "17us/dispatch" theory is DEAD (R21's delta was idx re-streaming, not
// launch cost). Kernel boundaries < software barriers w/ coherence fences.
// This round: revert to R19 skeleton (755us, verified) + 3 low-risk fixes:
// (1) scatter1 512 blocks x 1024 threads, NREP=8 -- same global atomic-chain
//     length (R20 lesson), 4x waves/CU for store-latency hiding. 44->~25us.
// (2) scatter2 U+I merged into one 294-block dispatch (-8us serialization).
// (3) init+zero_pads merged; stU/stI carved separately (no tauH aliasing).
// SpMM/transposes byte-identical to R19 (at their divergent-gather floor:
// width/ILP/sort-invariant per R15/R16/R17/R19). Predict 755 -> ~715-725.
// ---------------------------------------------------------------------------

struct __align__(8) Half4 { __half2 a, b; };
struct Coeffs { float v[ORDER + 1]; };

#define SLOT ((size_t)(NITEMS + 1) * BATCH)        // fp16 tau slot incl. zero row

__device__ __forceinline__ void acc_pk(float4& acc, Half4 v0, Half4 v1,
                                       Half4 v2, Half4 v3) {
    __half2 sa = __hadd2(__hadd2(v0.a, v1.a), __hadd2(v2.a, v3.a));
    __half2 sb = __hadd2(__hadd2(v0.b, v1.b), __hadd2(v2.b, v3.b));
    float2 fa = __half22float2(sa);
    float2 fb = __half22float2(sb);
    acc.x += fa.x; acc.y += fa.y; acc.z += fb.x; acc.w += fb.y;
}

__device__ __forceinline__ Half4 to_h4(float x, float y, float z, float w) {
    Half4 h;
    h.a = __floats2half2_rn(x, y);
    h.b = __floats2half2_rn(z, w);
    return h;
}

// ---------------------------------------------------------------------------
// init: reservations + pad rows (stU/stI no longer alias tauHall -> safe here)
// ---------------------------------------------------------------------------
__global__ void init_all(int* __restrict__ bcurU, int* __restrict__ bcurI,
                         __half* __restrict__ tauHall, __half* __restrict__ ybuf) {
    int t = threadIdx.x;
    for (int i = t; i < NBUCKU; i += 256) bcurU[i] = i * CAPU;
    for (int i = t; i < NBUCKI; i += 256) bcurI[i] = i * CAPI;
    if (t < BATCH) {
        for (int k = 0; k <= ORDER; ++k)
            tauHall[(size_t)k * SLOT + (size_t)NITEMS * BATCH + t] = __float2half(0.f);
        ybuf[(size_t)NUSERS * BATCH + t] = __float2half(0.f);
    }
}

// ---------------------------------------------------------------------------
// scatter1: 512 blocks (global atomic-chain length preserved) x 1024 threads
// (4x TLP for scattered-store latency hiding), 8 LDS sub-counters.
// ---------------------------------------------------------------------------
__global__ void scatter1(const int* __restrict__ row, const int* __restrict__ col,
                         int* __restrict__ bcurU, int* __restrict__ bcurI,
                         int* __restrict__ stU, int* __restrict__ stI, int nnz) {
    __shared__ int cU[NREP * NBUCKU];
    __shared__ int cI[NREP * NBUCKI];
    const int tid = threadIdx.x;
    const int chunk = (nnz + S1_BLOCKS - 1) / S1_BLOCKS;
    const int b0 = blockIdx.x * chunk;
    const int e0 = min(b0 + chunk, nnz);
    const int sw = S1_SW(tid);
    for (int t = tid; t < NREP * NBUCKU; t += S1_THREADS) cU[t] = 0;
    for (int t = tid; t < NREP * NBUCKI; t += S1_THREADS) cI[t] = 0;
    __syncthreads();
    for (int i = b0 + tid; i < e0; i += S1_THREADS) {
        atomicAdd(&cU[sw * NBUCKU + (row[i] >> BSHIFT)], 1);
        atomicAdd(&cI[sw * NBUCKI + (col[i] >> BSHIFT)], 1);
    }
    __syncthreads();
    for (int t = tid; t < NBUCKU; t += S1_THREADS) {
        int c[NREP], tot = 0;
        #pragma unroll
        for (int j = 0; j < NREP; ++j) { c[j] = cU[j * NBUCKU + t]; tot += c[j]; }
        int base = (tot > 0) ? atomicAdd(&bcurU[t], tot) : 0;
        #pragma unroll
        for (int j = 0; j < NREP; ++j) { cU[j * NBUCKU + t] = base; base += c[j]; }
    }
    for (int t = tid; t < NBUCKI; t += S1_THREADS) {
        int c[NREP], tot = 0;
        #pragma unroll
        for (int j = 0; j < NREP; ++j) { c[j] = cI[j * NBUCKI + t]; tot += c[j]; }
        int base = (tot > 0) ? atomicAdd(&bcurI[t], tot) : 0;
        #pragma unroll
        for (int j = 0; j < NREP; ++j) { cI[j * NBUCKI + t] = base; base += c[j]; }
    }
    __syncthreads();
    for (int i = b0 + tid; i < e0; i += S1_THREADS) {
        int r = row[i], c = col[i];
        int pu = atomicAdd(&cU[sw * NBUCKU + (r >> BSHIFT)], 1);
        stU[pu] = ((r & (BROWS - 1)) << 17) | c;
        int pi = atomicAdd(&cI[sw * NBUCKI + (c >> BSHIFT)], 1);
        stI[pi] = ((c & (BROWS - 1)) << 17) | r;
    }
}

// ---------------------------------------------------------------------------
// scatter2: U and I merged into one dispatch (294 blocks)
// ---------------------------------------------------------------------------
__device__ void scatter2_body(int bucket, const int* __restrict__ bcur,
                              const int* __restrict__ st, int* __restrict__ ptr,
                              int* __restrict__ degOut, int* __restrict__ outIdx,
                              int nrows, int cap, int dummyIdx, int* sm) {
    int* deg = sm;                      // BROWS
    int* ps  = sm + BROWS;              // 256
    int* cur = sm + BROWS + 256;        // BROWS
    int* rs  = sm + 2 * BROWS + 256;    // BROWS
    const int rbase = bucket << BSHIFT;
    const int nr = min(BROWS, nrows - rbase);
    const int lo = bucket * cap;
    const int hi = bcur[bucket];
    const int t = threadIdx.x;
    deg[2 * t] = 0;
    deg[2 * t + 1] = 0;
    __syncthreads();
    for (int j = lo + t; j < hi; j += 256)
        atomicAdd(&deg[st[j] >> 17], 1);
    __syncthreads();
    int a = deg[2 * t];
    int b = deg[2 * t + 1];
    int pa = (a + 15) & ~15;
    int pb = (b + 15) & ~15;
    ps[t] = pa + pb;
    __syncthreads();
    for (int off = 1; off < 256; off <<= 1) {
        int u = (t >= off) ? ps[t - off] : 0;
        __syncthreads();
        ps[t] += u;
        __syncthreads();
    }
    int excl = (t > 0) ? ps[t - 1] : 0;
    int p0 = lo + excl;
    int p1 = p0 + pa;
    rs[2 * t] = p0;
    rs[2 * t + 1] = p1;
    cur[2 * t] = p0;
    cur[2 * t + 1] = p1;
    if (2 * t < nr)     { ptr[rbase + 2 * t] = p0;     degOut[rbase + 2 * t] = a; }
    if (2 * t + 1 < nr) { ptr[rbase + 2 * t + 1] = p1; degOut[rbase + 2 * t + 1] = b; }
    __syncthreads();
    for (int j = lo + t; j < hi; j += 256) {
        int v = st[j];
        int p = atomicAdd(&cur[v >> 17], 1);
        outIdx[p] = v & 0x1FFFF;
    }
    __syncthreads();
    for (int i = t; i < nr; i += 256) {
        int endReal = cur[i];
        int endPad  = rs[i] + ((deg[i] + 15) & ~15);
        for (int j = endReal; j < endPad; ++j) outIdx[j] = dummyIdx;
    }
}

__global__ void scatter2_both(const int* __restrict__ bcurU, const int* __restrict__ stU,
                              int* __restrict__ uptr, int* __restrict__ udeg,
                              int* __restrict__ ucol,
                              const int* __restrict__ bcurI, const int* __restrict__ stI,
                              int* __restrict__ iptr, int* __restrict__ ideg,
                              int* __restrict__ irow) {
    __shared__ int sm[1792];
    if (blockIdx.x < NBUCKU)
        scatter2_body(blockIdx.x, bcurU, stU, uptr, udeg, ucol,
                      NUSERS, CAPU, NITEMS, sm);
    else
        scatter2_body(blockIdx.x - NBUCKU, bcurI, stI, iptr, ideg, irow,
                      NITEMS, CAPI, NUSERS, sm);
}

// ---------------------------------------------------------------------------
// transposes (R19, verified)
// ---------------------------------------------------------------------------
__global__ void transpose_scale_k(const float* __restrict__ in,
                                  const int* __restrict__ ideg,
                                  float* __restrict__ out,
                                  __half* __restrict__ outH) {
    __shared__ float tile[32][33];
    const int cb = blockIdx.x * 32;
    const int rb = blockIdx.y * 32;
    for (int i = threadIdx.y; i < 32; i += 8) {
        int r = rb + i, c = cb + threadIdx.x;
        if (r < BATCH && c < NITEMS) tile[i][threadIdx.x] = in[(size_t)r * NITEMS + c];
    }
    __syncthreads();
    for (int i = threadIdx.y; i < 32; i += 8) {
        int c = cb + i, r = rb + threadIdx.x;
        if (c < NITEMS && r < BATCH) {
            int d = ideg[c];
            float dis = (d > 0) ? rsqrtf((float)d) : 0.0f;
            float v = dis * tile[threadIdx.x][i];
            out[(size_t)c * BATCH + r] = v;
            outH[(size_t)c * BATCH + r] = __float2half(v);
        }
    }
}

__global__ void transpose_out_k(const __half* __restrict__ tauHall,
                                const float* __restrict__ signal,
                                const int* __restrict__ ideg, float csum, Coeffs cf,
                                float* __restrict__ out) {
    __shared__ float tile[32][33];
    const int cb = blockIdx.x * 32;
    const int rb = blockIdx.y * 32;
    for (int i = threadIdx.y; i < 32; i += 8) {
        int r = rb + i, c = cb + threadIdx.x;
        if (r < NITEMS && c < BATCH) {
            size_t base = (size_t)r * BATCH + c;
            float s = 0.f;
            #pragma unroll
            for (int k = 0; k <= ORDER; ++k)
                s += cf.v[k] * __half2float(tauHall[(size_t)k * SLOT + base]);
            tile[i][threadIdx.x] = s;
        }
    }
    __syncthreads();
    for (int i = threadIdx.y; i < 32; i += 8) {
        int c = cb + i, r = rb + threadIdx.x;
        if (c < BATCH && r < NITEMS) {
            int d = ideg[r];
            float v = (d > 0) ? sqrtf((float)d) * tile[threadIdx.x][i]
                              : csum * signal[(size_t)c * NITEMS + r];
            out[(size_t)c * NITEMS + r] = v;
        }
    }
}

// ---------------------------------------------------------------------------
// R19 gather core (verified): int4 idx loads + 32-bit byte offsets.
// ---------------------------------------------------------------------------
__device__ __forceinline__ void gather4_p(const int* __restrict__ idx,
                                          const Half4* __restrict__ x,
                                          const int* b, const int* n,
                                          int sub, int bh, float4* a) {
    const char* __restrict__ xb = (const char*)x;
    const char* __restrict__ ib = (const char*)idx;
    const unsigned bhoff = (unsigned)bh << 3;
    unsigned jb[4];
    int nmax = 0;
    #pragma unroll
    for (int q = 0; q < 4; ++q) {
        jb[q] = ((unsigned)b[q] << 2) + ((unsigned)sub << 4);
        nmax = max(nmax, n[q]);
    }
    for (int it = 0; it < nmax; ++it) {
        #pragma unroll
        for (int q = 0; q < 4; ++q) {
            if (it < n[q]) {
                int4 ii = *(const int4*)(ib + jb[q]);
                Half4 v0 = *(const Half4*)(xb + (((unsigned)ii.x << 7) + bhoff));
                Half4 v1 = *(const Half4*)(xb + (((unsigned)ii.y << 7) + bhoff));
                Half4 v2 = *(const Half4*)(xb + (((unsigned)ii.z << 7) + bhoff));
                Half4 v3 = *(const Half4*)(xb + (((unsigned)ii.w << 7) + bhoff));
                acc_pk(a[q], v0, v1, v2, v3);
                jb[q] += 64;
            }
        }
    }
    #pragma unroll
    for (int q = 0; q < 4; ++q) {
        a[q].x += __shfl_xor(a[q].x, 16); a[q].y += __shfl_xor(a[q].y, 16);
        a[q].z += __shfl_xor(a[q].z, 16); a[q].w += __shfl_xor(a[q].w, 16);
        a[q].x += __shfl_xor(a[q].x, 32); a[q].y += __shfl_xor(a[q].y, 32);
        a[q].z += __shfl_xor(a[q].z, 32); a[q].w += __shfl_xor(a[q].w, 32);
    }
}

__global__ void spmm_user(const int* __restrict__ ptr, const int* __restrict__ deg,
                          const int* __restrict__ idx,
                          const Half4* __restrict__ tauH, Half4* __restrict__ y) {
    const int lane = threadIdx.x & 63;
    const int w = (blockIdx.x * blockDim.x + threadIdx.x) >> 6;
    const int H = NUSERS / 4;
    if (w >= H) return;
    int r[4] = {w, w + H, w + 2 * H, w + 3 * H};
    const int sub = lane >> 4;
    const int bh  = lane & 15;
    int b[4], d[4], n[4];
    #pragma unroll
    for (int q = 0; q < 4; ++q) {
        b[q] = ptr[r[q]];
        d[q] = deg[r[q]];
        n[q] = (d[q] + 15) >> 4;
    }
    float4 a[4] = {{0,0,0,0},{0,0,0,0},{0,0,0,0},{0,0,0,0}};
    gather4_p(idx, tauH, b, n, sub, bh, a);
    if (sub == 0) {
        #pragma unroll
        for (int q = 0; q < 4; ++q) {
            float s = (d[q] > 0) ? 1.0f / (float)d[q] : 0.0f;
            y[(size_t)r[q] * 16 + bh] = to_h4(s * a[q].x, s * a[q].y, s * a[q].z, s * a[q].w);
        }
    }
}

__global__ void spmm_item_first(const int* __restrict__ ptr, const int* __restrict__ deg,
                                const int* __restrict__ idx, const Half4* __restrict__ y,
                                const float* __restrict__ tau0, float* __restrict__ tau1,
                                Half4* __restrict__ tauH1) {
    const int lane = threadIdx.x & 63;
    const int w = (blockIdx.x * blockDim.x + threadIdx.x) >> 6;
    const int H = NITEMS / 4;
    if (w >= H) return;
    int r[4] = {w, w + H, w + 2 * H, w + 3 * H};
    const int sub = lane >> 4;
    const int bh  = lane & 15;
    int b[4], d[4], n[4];
    #pragma unroll
    for (int q = 0; q < 4; ++q) {
        b[q] = ptr[r[q]];
        d[q] = deg[r[q]];
        n[q] = (d[q] + 15) >> 4;
    }
    float4 a[4] = {{0,0,0,0},{0,0,0,0},{0,0,0,0},{0,0,0,0}};
    gather4_p(idx, y, b, n, sub, bh, a);
    if (sub == 0) {
        #pragma unroll
        for (int q = 0; q < 4; ++q) {
            float inv = (d[q] > 0) ? 1.0f / (float)d[q] : 0.0f;
            float s2 = 2.0f * inv;
            size_t base = (size_t)r[q] * BATCH + (bh << 2);
            float4 t0v = *(const float4*)&tau0[base];
            float4 t;
            t.x = t0v.x - s2 * a[q].x; t.y = t0v.y - s2 * a[q].y;
            t.z = t0v.z - s2 * a[q].z; t.w = t0v.w - s2 * a[q].w;
            *(float4*)&tau1[base] = t;
            tauH1[(size_t)r[q] * 16 + bh] = to_h4(t.x, t.y, t.z, t.w);
        }
    }
}

__global__ void spmm_item_k(const int* __restrict__ ptr, const int* __restrict__ deg,
                            const int* __restrict__ idx, const Half4* __restrict__ y,
                            const float* __restrict__ tau1, float* __restrict__ tau0,
                            Half4* __restrict__ tauHk) {
    const int lane = threadIdx.x & 63;
    const int w = (blockIdx.x * blockDim.x + threadIdx.x) >> 6;
    const int H = NITEMS / 4;
    if (w >= H) return;
    int r[4] = {w, w + H, w + 2 * H, w + 3 * H};
    const int sub = lane >> 4;
    const int bh  = lane & 15;
    int b[4], d[4], n[4];
    #pragma unroll
    for (int q = 0; q < 4; ++q) {
        b[q] = ptr[r[q]];
        d[q] = deg[r[q]];
        n[q] = (d[q] + 15) >> 4;
    }
    float4 a[4] = {{0,0,0,0},{0,0,0,0},{0,0,0,0},{0,0,0,0}};
    gather4_p(idx, y, b, n, sub, bh, a);
    if (sub == 0) {
        #pragma unroll
        for (int q = 0; q < 4; ++q) {
            float inv = (d[q] > 0) ? 1.0f / (float)d[q] : 0.0f;
            float s4 = 4.0f * inv;
            size_t base = (size_t)r[q] * BATCH + (bh << 2);
            float4 t1v = *(const float4*)&tau1[base];
            float4 t0v = *(const float4*)&tau0[base];
            float4 t2;
            t2.x = 2.0f * t1v.x - s4 * a[q].x - t0v.x;
            t2.y = 2.0f * t1v.y - s4 * a[q].y - t0v.y;
            t2.z = 2.0f * t1v.z - s4 * a[q].z - t0v.z;
            t2.w = 2.0f * t1v.w - s4 * a[q].w - t0v.w;
            *(float4*)&tau0[base] = t2;
            tauHk[(size_t)r[q] * 16 + bh] = to_h4(t2.x, t2.y, t2.z, t2.w);
        }
    }
}

// ---------------------------------------------------------------------------
// Host-side exact replica of reference cheby_coeffs
// ---------------------------------------------------------------------------
static void cheby_coeffs_host(float* c) {
    const int order = ORDER, flatness = 2;
    const double PI = 3.14159265358979323846;
    double tgt[ORDER + 1], nodes[ORDER + 1];
    for (int x = 0; x <= order; ++x) {
        double xv = cos((double)(order - x) / order * PI);
        xv = nearbyint(xv * 1000.0) / 1000.0;
        double t = (xv < 0.0) ? pow(-xv, (double)flatness) * 0.5 + 0.5
                              : pow(xv, (double)flatness) * (-0.5) + 0.5;
        tgt[x] = nearbyint(t * 1000.0) / 1000.0;
    }
    for (int k = 1; k <= order + 1; ++k)
        nodes[k - 1] = cos((order + 1 + 0.5 - k) / (double)(order + 1) * PI);

    double prev[ORDER + 1], cur[ORDER + 1], nxt[ORDER + 1];
    double sums[ORDER + 1];
    double s0 = 0, s1 = 0;
    for (int i = 0; i <= order; ++i) {
        prev[i] = tgt[i];
        cur[i]  = nodes[i] * tgt[i];
        s0 += prev[i];
        s1 += cur[i];
    }
    sums[0] = s0; sums[1] = s1;
    for (int j = 2; j <= order; ++j) {
        double s = 0;
        for (int i = 0; i <= order; ++i) {
            nxt[i] = nodes[i] * cur[i] * 2.0 - prev[i];
            s += nxt[i];
        }
        sums[j] = s;
        for (int i = 0; i <= order; ++i) { prev[i] = cur[i]; cur[i] = nxt[i]; }
    }
    for (int j = 0; j <= order; ++j)
        c[j] = (float)(sums[j] * (2.0 / (order + 1)));
    c[0] *= 0.5f;
}

extern "C" void kernel_launch(void* const* d_in, const int* in_sizes, int n_in,
                              void* d_out, int out_size, void* d_ws, size_t ws_size,
                              hipStream_t stream) {
    const float* signal = (const float*)d_in[0];   // [BATCH, NITEMS]
    const int*   row    = (const int*)d_in[2];     // [NNZ] -> users
    const int*   col    = (const int*)d_in[3];     // [NNZ] -> items
    const int nnz = in_sizes[1];

    char* wsb = (char*)d_ws;
    size_t off = 0;
    auto carve = [&](size_t nbytes) {
        void* p = wsb + off;
        off += (nbytes + 255) & ~(size_t)255;
        return p;
    };
    const size_t NB = (size_t)NITEMS * BATCH;
    const size_t NEU = (size_t)NBUCKU * CAPU;
    const size_t NEI = (size_t)NBUCKI * CAPI;
    float*  tauA   = (float*)carve(NB * 4);
    float*  tauB   = (float*)carve(NB * 4);
    __half* tauHall = (__half*)carve((ORDER + 1) * SLOT * 2);
    Half4*  ybuf   = (Half4*)carve(((size_t)NUSERS + 1) * BATCH * 2);
    int*    uptr   = (int*)carve(NUSERS * 4);
    int*    iptr   = (int*)carve(NITEMS * 4);
    int*    udeg   = (int*)carve(NUSERS * 4);
    int*    ideg   = (int*)carve(NITEMS * 4);
    int*    bcurU  = (int*)carve(NBUCKU * 4);
    int*    bcurI  = (int*)carve(NBUCKI * 4);
    int*    ucol   = (int*)carve(NEU * 4);
    int*    irow   = (int*)carve(NEI * 4);
    int*    stU    = (int*)carve(NEU * 4);       // separate carve: no aliasing
    int*    stI    = (int*)carve(NEI * 4);
    (void)ws_size;

    float c[ORDER + 1];
    cheby_coeffs_host(c);
    Coeffs cf;
    float csum = 0.f;
    for (int k = 0; k <= ORDER; ++k) { cf.v[k] = c[k]; csum += c[k]; }

    // ---- CSR build ----
    init_all<<<1, 256, 0, stream>>>(bcurU, bcurI, tauHall, (__half*)ybuf);
    scatter1<<<S1_BLOCKS, S1_THREADS, 0, stream>>>(row, col, bcurU, bcurI, stU, stI, nnz);
    scatter2_both<<<NBUCKU + NBUCKI, 256, 0, stream>>>(bcurU, stU, uptr, udeg, ucol,
                                                       bcurI, stI, iptr, ideg, irow);

    // ---- tau0 (fp32 + fp16 slot 0) ----
    dim3 tb(32, 8);
    transpose_scale_k<<<dim3((NITEMS + 31) / 32, (BATCH + 31) / 32), tb, 0, stream>>>(
        signal, ideg, tauA, tauHall);

    const int ug = ((NUSERS / 4) * 64 + 255) / 256;   // user: 4 rows/wave (padded)
    const int ig = ((NITEMS / 4) * 64 + 255) / 256;   // item: 4 rows/wave

    // ---- k = 1 ----
    spmm_user<<<ug, 256, 0, stream>>>(uptr, udeg, ucol, (const Half4*)tauHall, ybuf);
    spmm_item_first<<<ig, 256, 0, stream>>>(iptr, ideg, irow, ybuf, tauA, tauB,
                                            (Half4*)(tauHall + SLOT));

    float* t0 = tauA;
    float* t1 = tauB;
    for (int k = 2; k <= ORDER; ++k) {
        spmm_user<<<ug, 256, 0, stream>>>(uptr, udeg, ucol,
                                          (const Half4*)(tauHall + (size_t)(k - 1) * SLOT), ybuf);
        spmm_item_k<<<ig, 256, 0, stream>>>(iptr, ideg, irow, ybuf, t1, t0,
                                            (Half4*)(tauHall + (size_t)k * SLOT));
        float* tmp = t0; t0 = t1; t1 = tmp;
    }

    // ---- d_out = sqrt(di) * sum_k c_k tauH_k, transposed ----
    transpose_out_k<<<dim3((BATCH + 31) / 32, (NITEMS + 31) / 32), tb, 0, stream>>>(
        tauHall, signal, ideg, csum, cf, (float*)d_out);
}

// Round 9
// 711.412 us; speedup vs baseline: 7.7475x; 1.0208x over previous
//
#include <hip/hip_runtime.h>
#include <hip/hip_fp16.h>
#include <math.h>

#define NUSERS 100000
#define NITEMS 50000
#define BATCH  64
#define ORDER  8
#define BSHIFT 9                                   // 512 rows per bucket
#define BROWS  (1 << BSHIFT)
#define NBUCKU ((NUSERS + BROWS - 1) >> BSHIFT)    // 196
#define NBUCKI ((NITEMS + BROWS - 1) >> BSHIFT)    // 98
#define CAPU 16384
#define CAPI 24576
#define S1_BLOCKS 512
#define S1_THREADS 1024
#define NREP 8
#define S1_SW(t) (((t) >> 6) & (NREP - 1))
#define S2_THREADS 1024

// ---------------------------------------------------------------------------
// R25: R24 landed as predicted (755->726; scatter1 fix confirmed). New top
// dispatch: scatter2_both 48us @ 6.9% occupancy, VALU 2.4%, HBM 12% --
// latency-bound underfill (294 blocks x 4 waves ~ 4.6 waves/CU offered; the
// 256-stride count/placement loops + 16-barrier scan idle the rest). Fix:
// S2_THREADS=1024 (4x TLP on count/placement/pad loops; scan stays on
// threads 0-255 with all-thread barriers). Everything else byte-identical.
// Predict: scatter2 48 -> ~18-25us, total 726 -> ~695-705; SpMM dispatches
// (~38-40us x16 = 84% of runtime) surface in top-5 next round for diagnosis.
// ---------------------------------------------------------------------------

struct __align__(8) Half4 { __half2 a, b; };
struct Coeffs { float v[ORDER + 1]; };

#define SLOT ((size_t)(NITEMS + 1) * BATCH)        // fp16 tau slot incl. zero row

__device__ __forceinline__ void acc_pk(float4& acc, Half4 v0, Half4 v1,
                                       Half4 v2, Half4 v3) {
    __half2 sa = __hadd2(__hadd2(v0.a, v1.a), __hadd2(v2.a, v3.a));
    __half2 sb = __hadd2(__hadd2(v0.b, v1.b), __hadd2(v2.b, v3.b));
    float2 fa = __half22float2(sa);
    float2 fb = __half22float2(sb);
    acc.x += fa.x; acc.y += fa.y; acc.z += fb.x; acc.w += fb.y;
}

__device__ __forceinline__ Half4 to_h4(float x, float y, float z, float w) {
    Half4 h;
    h.a = __floats2half2_rn(x, y);
    h.b = __floats2half2_rn(z, w);
    return h;
}

// ---------------------------------------------------------------------------
// init: reservations + pad rows
// ---------------------------------------------------------------------------
__global__ void init_all(int* __restrict__ bcurU, int* __restrict__ bcurI,
                         __half* __restrict__ tauHall, __half* __restrict__ ybuf) {
    int t = threadIdx.x;
    for (int i = t; i < NBUCKU; i += 256) bcurU[i] = i * CAPU;
    for (int i = t; i < NBUCKI; i += 256) bcurI[i] = i * CAPI;
    if (t < BATCH) {
        for (int k = 0; k <= ORDER; ++k)
            tauHall[(size_t)k * SLOT + (size_t)NITEMS * BATCH + t] = __float2half(0.f);
        ybuf[(size_t)NUSERS * BATCH + t] = __float2half(0.f);
    }
}

// ---------------------------------------------------------------------------
// scatter1: 512 blocks x 1024 threads, 8 LDS sub-counters (R24, verified)
// ---------------------------------------------------------------------------
__global__ void scatter1(const int* __restrict__ row, const int* __restrict__ col,
                         int* __restrict__ bcurU, int* __restrict__ bcurI,
                         int* __restrict__ stU, int* __restrict__ stI, int nnz) {
    __shared__ int cU[NREP * NBUCKU];
    __shared__ int cI[NREP * NBUCKI];
    const int tid = threadIdx.x;
    const int chunk = (nnz + S1_BLOCKS - 1) / S1_BLOCKS;
    const int b0 = blockIdx.x * chunk;
    const int e0 = min(b0 + chunk, nnz);
    const int sw = S1_SW(tid);
    for (int t = tid; t < NREP * NBUCKU; t += S1_THREADS) cU[t] = 0;
    for (int t = tid; t < NREP * NBUCKI; t += S1_THREADS) cI[t] = 0;
    __syncthreads();
    for (int i = b0 + tid; i < e0; i += S1_THREADS) {
        atomicAdd(&cU[sw * NBUCKU + (row[i] >> BSHIFT)], 1);
        atomicAdd(&cI[sw * NBUCKI + (col[i] >> BSHIFT)], 1);
    }
    __syncthreads();
    for (int t = tid; t < NBUCKU; t += S1_THREADS) {
        int c[NREP], tot = 0;
        #pragma unroll
        for (int j = 0; j < NREP; ++j) { c[j] = cU[j * NBUCKU + t]; tot += c[j]; }
        int base = (tot > 0) ? atomicAdd(&bcurU[t], tot) : 0;
        #pragma unroll
        for (int j = 0; j < NREP; ++j) { cU[j * NBUCKU + t] = base; base += c[j]; }
    }
    for (int t = tid; t < NBUCKI; t += S1_THREADS) {
        int c[NREP], tot = 0;
        #pragma unroll
        for (int j = 0; j < NREP; ++j) { c[j] = cI[j * NBUCKI + t]; tot += c[j]; }
        int base = (tot > 0) ? atomicAdd(&bcurI[t], tot) : 0;
        #pragma unroll
        for (int j = 0; j < NREP; ++j) { cI[j * NBUCKI + t] = base; base += c[j]; }
    }
    __syncthreads();
    for (int i = b0 + tid; i < e0; i += S1_THREADS) {
        int r = row[i], c = col[i];
        int pu = atomicAdd(&cU[sw * NBUCKU + (r >> BSHIFT)], 1);
        stU[pu] = ((r & (BROWS - 1)) << 17) | c;
        int pi = atomicAdd(&cI[sw * NBUCKI + (c >> BSHIFT)], 1);
        stI[pi] = ((c & (BROWS - 1)) << 17) | r;
    }
}

// ---------------------------------------------------------------------------
// scatter2: 1024 threads/block. Count/placement/pad loops stride 1024;
// the 256-wide scan runs on threads 0-255 with all-thread barriers.
// ---------------------------------------------------------------------------
__device__ void scatter2_body(int bucket, const int* __restrict__ bcur,
                              const int* __restrict__ st, int* __restrict__ ptr,
                              int* __restrict__ degOut, int* __restrict__ outIdx,
                              int nrows, int cap, int dummyIdx, int* sm) {
    int* deg = sm;                      // BROWS
    int* ps  = sm + BROWS;              // 256
    int* cur = sm + BROWS + 256;        // BROWS
    int* rs  = sm + 2 * BROWS + 256;    // BROWS
    const int rbase = bucket << BSHIFT;
    const int nr = min(BROWS, nrows - rbase);
    const int lo = bucket * cap;
    const int hi = bcur[bucket];
    const int t = threadIdx.x;
    for (int i = t; i < BROWS; i += S2_THREADS) deg[i] = 0;
    __syncthreads();
    for (int j = lo + t; j < hi; j += S2_THREADS)
        atomicAdd(&deg[st[j] >> 17], 1);
    __syncthreads();
    int a = 0, b = 0, pa = 0, pb = 0;
    if (t < 256) {
        a = deg[2 * t];
        b = deg[2 * t + 1];
        pa = (a + 15) & ~15;
        pb = (b + 15) & ~15;
        ps[t] = pa + pb;
    }
    __syncthreads();
    for (int off = 1; off < 256; off <<= 1) {
        int u = (t >= off && t < 256) ? ps[t - off] : 0;
        __syncthreads();
        if (t < 256) ps[t] += u;
        __syncthreads();
    }
    if (t < 256) {
        int excl = (t > 0) ? ps[t - 1] : 0;
        int p0 = lo + excl;
        int p1 = p0 + pa;
        rs[2 * t] = p0;
        rs[2 * t + 1] = p1;
        cur[2 * t] = p0;
        cur[2 * t + 1] = p1;
        if (2 * t < nr)     { ptr[rbase + 2 * t] = p0;     degOut[rbase + 2 * t] = a; }
        if (2 * t + 1 < nr) { ptr[rbase + 2 * t + 1] = p1; degOut[rbase + 2 * t + 1] = b; }
    }
    __syncthreads();
    for (int j = lo + t; j < hi; j += S2_THREADS) {
        int v = st[j];
        int p = atomicAdd(&cur[v >> 17], 1);
        outIdx[p] = v & 0x1FFFF;
    }
    __syncthreads();
    for (int i = t; i < nr; i += S2_THREADS) {
        int endReal = cur[i];
        int endPad  = rs[i] + ((deg[i] + 15) & ~15);
        for (int j = endReal; j < endPad; ++j) outIdx[j] = dummyIdx;
    }
}

__global__ void scatter2_both(const int* __restrict__ bcurU, const int* __restrict__ stU,
                              int* __restrict__ uptr, int* __restrict__ udeg,
                              int* __restrict__ ucol,
                              const int* __restrict__ bcurI, const int* __restrict__ stI,
                              int* __restrict__ iptr, int* __restrict__ ideg,
                              int* __restrict__ irow) {
    __shared__ int sm[1792];
    if (blockIdx.x < NBUCKU)
        scatter2_body(blockIdx.x, bcurU, stU, uptr, udeg, ucol,
                      NUSERS, CAPU, NITEMS, sm);
    else
        scatter2_body(blockIdx.x - NBUCKU, bcurI, stI, iptr, ideg, irow,
                      NITEMS, CAPI, NUSERS, sm);
}

// ---------------------------------------------------------------------------
// transposes (R19, verified)
// ---------------------------------------------------------------------------
__global__ void transpose_scale_k(const float* __restrict__ in,
                                  const int* __restrict__ ideg,
                                  float* __restrict__ out,
                                  __half* __restrict__ outH) {
    __shared__ float tile[32][33];
    const int cb = blockIdx.x * 32;
    const int rb = blockIdx.y * 32;
    for (int i = threadIdx.y; i < 32; i += 8) {
        int r = rb + i, c = cb + threadIdx.x;
        if (r < BATCH && c < NITEMS) tile[i][threadIdx.x] = in[(size_t)r * NITEMS + c];
    }
    __syncthreads();
    for (int i = threadIdx.y; i < 32; i += 8) {
        int c = cb + i, r = rb + threadIdx.x;
        if (c < NITEMS && r < BATCH) {
            int d = ideg[c];
            float dis = (d > 0) ? rsqrtf((float)d) : 0.0f;
            float v = dis * tile[threadIdx.x][i];
            out[(size_t)c * BATCH + r] = v;
            outH[(size_t)c * BATCH + r] = __float2half(v);
        }
    }
}

__global__ void transpose_out_k(const __half* __restrict__ tauHall,
                                const float* __restrict__ signal,
                                const int* __restrict__ ideg, float csum, Coeffs cf,
                                float* __restrict__ out) {
    __shared__ float tile[32][33];
    const int cb = blockIdx.x * 32;
    const int rb = blockIdx.y * 32;
    for (int i = threadIdx.y; i < 32; i += 8) {
        int r = rb + i, c = cb + threadIdx.x;
        if (r < NITEMS && c < BATCH) {
            size_t base = (size_t)r * BATCH + c;
            float s = 0.f;
            #pragma unroll
            for (int k = 0; k <= ORDER; ++k)
                s += cf.v[k] * __half2float(tauHall[(size_t)k * SLOT + base]);
            tile[i][threadIdx.x] = s;
        }
    }
    __syncthreads();
    for (int i = threadIdx.y; i < 32; i += 8) {
        int c = cb + i, r = rb + threadIdx.x;
        if (c < BATCH && r < NITEMS) {
            int d = ideg[r];
            float v = (d > 0) ? sqrtf((float)d) * tile[threadIdx.x][i]
                              : csum * signal[(size_t)c * NITEMS + r];
            out[(size_t)c * NITEMS + r] = v;
        }
    }
}

// ---------------------------------------------------------------------------
// R19 gather core (verified): int4 idx loads + 32-bit byte offsets.
// ---------------------------------------------------------------------------
__device__ __forceinline__ void gather4_p(const int* __restrict__ idx,
                                          const Half4* __restrict__ x,
                                          const int* b, const int* n,
                                          int sub, int bh, float4* a) {
    const char* __restrict__ xb = (const char*)x;
    const char* __restrict__ ib = (const char*)idx;
    const unsigned bhoff = (unsigned)bh << 3;
    unsigned jb[4];
    int nmax = 0;
    #pragma unroll
    for (int q = 0; q < 4; ++q) {
        jb[q] = ((unsigned)b[q] << 2) + ((unsigned)sub << 4);
        nmax = max(nmax, n[q]);
    }
    for (int it = 0; it < nmax; ++it) {
        #pragma unroll
        for (int q = 0; q < 4; ++q) {
            if (it < n[q]) {
                int4 ii = *(const int4*)(ib + jb[q]);
                Half4 v0 = *(const Half4*)(xb + (((unsigned)ii.x << 7) + bhoff));
                Half4 v1 = *(const Half4*)(xb + (((unsigned)ii.y << 7) + bhoff));
                Half4 v2 = *(const Half4*)(xb + (((unsigned)ii.z << 7) + bhoff));
                Half4 v3 = *(const Half4*)(xb + (((unsigned)ii.w << 7) + bhoff));
                acc_pk(a[q], v0, v1, v2, v3);
                jb[q] += 64;
            }
        }
    }
    #pragma unroll
    for (int q = 0; q < 4; ++q) {
        a[q].x += __shfl_xor(a[q].x, 16); a[q].y += __shfl_xor(a[q].y, 16);
        a[q].z += __shfl_xor(a[q].z, 16); a[q].w += __shfl_xor(a[q].w, 16);
        a[q].x += __shfl_xor(a[q].x, 32); a[q].y += __shfl_xor(a[q].y, 32);
        a[q].z += __shfl_xor(a[q].z, 32); a[q].w += __shfl_xor(a[q].w, 32);
    }
}

__global__ void spmm_user(const int* __restrict__ ptr, const int* __restrict__ deg,
                          const int* __restrict__ idx,
                          const Half4* __restrict__ tauH, Half4* __restrict__ y) {
    const int lane = threadIdx.x & 63;
    const int w = (blockIdx.x * blockDim.x + threadIdx.x) >> 6;
    const int H = NUSERS / 4;
    if (w >= H) return;
    int r[4] = {w, w + H, w + 2 * H, w + 3 * H};
    const int sub = lane >> 4;
    const int bh  = lane & 15;
    int b[4], d[4], n[4];
    #pragma unroll
    for (int q = 0; q < 4; ++q) {
        b[q] = ptr[r[q]];
        d[q] = deg[r[q]];
        n[q] = (d[q] + 15) >> 4;
    }
    float4 a[4] = {{0,0,0,0},{0,0,0,0},{0,0,0,0},{0,0,0,0}};
    gather4_p(idx, tauH, b, n, sub, bh, a);
    if (sub == 0) {
        #pragma unroll
        for (int q = 0; q < 4; ++q) {
            float s = (d[q] > 0) ? 1.0f / (float)d[q] : 0.0f;
            y[(size_t)r[q] * 16 + bh] = to_h4(s * a[q].x, s * a[q].y, s * a[q].z, s * a[q].w);
        }
    }
}

__global__ void spmm_item_first(const int* __restrict__ ptr, const int* __restrict__ deg,
                                const int* __restrict__ idx, const Half4* __restrict__ y,
                                const float* __restrict__ tau0, float* __restrict__ tau1,
                                Half4* __restrict__ tauH1) {
    const int lane = threadIdx.x & 63;
    const int w = (blockIdx.x * blockDim.x + threadIdx.x) >> 6;
    const int H = NITEMS / 4;
    if (w >= H) return;
    int r[4] = {w, w + H, w + 2 * H, w + 3 * H};
    const int sub = lane >> 4;
    const int bh  = lane & 15;
    int b[4], d[4], n[4];
    #pragma unroll
    for (int q = 0; q < 4; ++q) {
        b[q] = ptr[r[q]];
        d[q] = deg[r[q]];
        n[q] = (d[q] + 15) >> 4;
    }
    float4 a[4] = {{0,0,0,0},{0,0,0,0},{0,0,0,0},{0,0,0,0}};
    gather4_p(idx, y, b, n, sub, bh, a);
    if (sub == 0) {
        #pragma unroll
        for (int q = 0; q < 4; ++q) {
            float inv = (d[q] > 0) ? 1.0f / (float)d[q] : 0.0f;
            float s2 = 2.0f * inv;
            size_t base = (size_t)r[q] * BATCH + (bh << 2);
            float4 t0v = *(const float4*)&tau0[base];
            float4 t;
            t.x = t0v.x - s2 * a[q].x; t.y = t0v.y - s2 * a[q].y;
            t.z = t0v.z - s2 * a[q].z; t.w = t0v.w - s2 * a[q].w;
            *(float4*)&tau1[base] = t;
            tauH1[(size_t)r[q] * 16 + bh] = to_h4(t.x, t.y, t.z, t.w);
        }
    }
}

__global__ void spmm_item_k(const int* __restrict__ ptr, const int* __restrict__ deg,
                            const int* __restrict__ idx, const Half4* __restrict__ y,
                            const float* __restrict__ tau1, float* __restrict__ tau0,
                            Half4* __restrict__ tauHk) {
    const int lane = threadIdx.x & 63;
    const int w = (blockIdx.x * blockDim.x + threadIdx.x) >> 6;
    const int H = NITEMS / 4;
    if (w >= H) return;
    int r[4] = {w, w + H, w + 2 * H, w + 3 * H};
    const int sub = lane >> 4;
    const int bh  = lane & 15;
    int b[4], d[4], n[4];
    #pragma unroll
    for (int q = 0; q < 4; ++q) {
        b[q] = ptr[r[q]];
        d[q] = deg[r[q]];
        n[q] = (d[q] + 15) >> 4;
    }
    float4 a[4] = {{0,0,0,0},{0,0,0,0},{0,0,0,0},{0,0,0,0}};
    gather4_p(idx, y, b, n, sub, bh, a);
    if (sub == 0) {
        #pragma unroll
        for (int q = 0; q < 4; ++q) {
            float inv = (d[q] > 0) ? 1.0f / (float)d[q] : 0.0f;
            float s4 = 4.0f * inv;
            size_t base = (size_t)r[q] * BATCH + (bh << 2);
            float4 t1v = *(const float4*)&tau1[base];
            float4 t0v = *(const float4*)&tau0[base];
            float4 t2;
            t2.x = 2.0f * t1v.x - s4 * a[q].x - t0v.x;
            t2.y = 2.0f * t1v.y - s4 * a[q].y - t0v.y;
            t2.z = 2.0f * t1v.z - s4 * a[q].z - t0v.z;
            t2.w = 2.0f * t1v.w - s4 * a[q].w - t0v.w;
            *(float4*)&tau0[base] = t2;
            tauHk[(size_t)r[q] * 16 + bh] = to_h4(t2.x, t2.y, t2.z, t2.w);
        }
    }
}

// ---------------------------------------------------------------------------
// Host-side exact replica of reference cheby_coeffs
// ---------------------------------------------------------------------------
static void cheby_coeffs_host(float* c) {
    const int order = ORDER, flatness = 2;
    const double PI = 3.14159265358979323846;
    double tgt[ORDER + 1], nodes[ORDER + 1];
    for (int x = 0; x <= order; ++x) {
        double xv = cos((double)(order - x) / order * PI);
        xv = nearbyint(xv * 1000.0) / 1000.0;
        double t = (xv < 0.0) ? pow(-xv, (double)flatness) * 0.5 + 0.5
                              : pow(xv, (double)flatness) * (-0.5) + 0.5;
        tgt[x] = nearbyint(t * 1000.0) / 1000.0;
    }
    for (int k = 1; k <= order + 1; ++k)
        nodes[k - 1] = cos((order + 1 + 0.5 - k) / (double)(order + 1) * PI);

    double prev[ORDER + 1], cur[ORDER + 1], nxt[ORDER + 1];
    double sums[ORDER + 1];
    double s0 = 0, s1 = 0;
    for (int i = 0; i <= order; ++i) {
        prev[i] = tgt[i];
        cur[i]  = nodes[i] * tgt[i];
        s0 += prev[i];
        s1 += cur[i];
    }
    sums[0] = s0; sums[1] = s1;
    for (int j = 2; j <= order; ++j) {
        double s = 0;
        for (int i = 0; i <= order; ++i) {
            nxt[i] = nodes[i] * cur[i] * 2.0 - prev[i];
            s += nxt[i];
        }
        sums[j] = s;
        for (int i = 0; i <= order; ++i) { prev[i] = cur[i]; cur[i] = nxt[i]; }
    }
    for (int j = 0; j <= order; ++j)
        c[j] = (float)(sums[j] * (2.0 / (order + 1)));
    c[0] *= 0.5f;
}

extern "C" void kernel_launch(void* const* d_in, const int* in_sizes, int n_in,
                              void* d_out, int out_size, void* d_ws, size_t ws_size,
                              hipStream_t stream) {
    const float* signal = (const float*)d_in[0];   // [BATCH, NITEMS]
    const int*   row    = (const int*)d_in[2];     // [NNZ] -> users
    const int*   col    = (const int*)d_in[3];     // [NNZ] -> items
    const int nnz = in_sizes[1];

    char* wsb = (char*)d_ws;
    size_t off = 0;
    auto carve = [&](size_t nbytes) {
        void* p = wsb + off;
        off += (nbytes + 255) & ~(size_t)255;
        return p;
    };
    const size_t NB = (size_t)NITEMS * BATCH;
    const size_t NEU = (size_t)NBUCKU * CAPU;
    const size_t NEI = (size_t)NBUCKI * CAPI;
    float*  tauA   = (float*)carve(NB * 4);
    float*  tauB   = (float*)carve(NB * 4);
    __half* tauHall = (__half*)carve((ORDER + 1) * SLOT * 2);
    Half4*  ybuf   = (Half4*)carve(((size_t)NUSERS + 1) * BATCH * 2);
    int*    uptr   = (int*)carve(NUSERS * 4);
    int*    iptr   = (int*)carve(NITEMS * 4);
    int*    udeg   = (int*)carve(NUSERS * 4);
    int*    ideg   = (int*)carve(NITEMS * 4);
    int*    bcurU  = (int*)carve(NBUCKU * 4);
    int*    bcurI  = (int*)carve(NBUCKI * 4);
    int*    ucol   = (int*)carve(NEU * 4);
    int*    irow   = (int*)carve(NEI * 4);
    int*    stU    = (int*)carve(NEU * 4);       // separate carve: no aliasing
    int*    stI    = (int*)carve(NEI * 4);
    (void)ws_size;

    float c[ORDER + 1];
    cheby_coeffs_host(c);
    Coeffs cf;
    float csum = 0.f;
    for (int k = 0; k <= ORDER; ++k) { cf.v[k] = c[k]; csum += c[k]; }

    // ---- CSR build ----
    init_all<<<1, 256, 0, stream>>>(bcurU, bcurI, tauHall, (__half*)ybuf);
    scatter1<<<S1_BLOCKS, S1_THREADS, 0, stream>>>(row, col, bcurU, bcurI, stU, stI, nnz);
    scatter2_both<<<NBUCKU + NBUCKI, S2_THREADS, 0, stream>>>(bcurU, stU, uptr, udeg, ucol,
                                                              bcurI, stI, iptr, ideg, irow);

    // ---- tau0 (fp32 + fp16 slot 0) ----
    dim3 tb(32, 8);
    transpose_scale_k<<<dim3((NITEMS + 31) / 32, (BATCH + 31) / 32), tb, 0, stream>>>(
        signal, ideg, tauA, tauHall);

    const int ug = ((NUSERS / 4) * 64 + 255) / 256;   // user: 4 rows/wave (padded)
    const int ig = ((NITEMS / 4) * 64 + 255) / 256;   // item: 4 rows/wave

    // ---- k = 1 ----
    spmm_user<<<ug, 256, 0, stream>>>(uptr, udeg, ucol, (const Half4*)tauHall, ybuf);
    spmm_item_first<<<ig, 256, 0, stream>>>(iptr, ideg, irow, ybuf, tauA, tauB,
                                            (Half4*)(tauHall + SLOT));

    float* t0 = tauA;
    float* t1 = tauB;
    for (int k = 2; k <= ORDER; ++k) {
        spmm_user<<<ug, 256, 0, stream>>>(uptr, udeg, ucol,
                                          (const Half4*)(tauHall + (size_t)(k - 1) * SLOT), ybuf);
        spmm_item_k<<<ig, 256, 0, stream>>>(iptr, ideg, irow, ybuf, t1, t0,
                                            (Half4*)(tauHall + (size_t)k * SLOT));
        float* tmp = t0; t0 = t1; t1 = tmp;
    }

    // ---- d_out = sqrt(di) * sum_k c_k tauH_k, transposed ----
    transpose_out_k<<<dim3((BATCH + 31) / 32, (NITEMS + 31) / 32), tb, 0, stream>>>(
        tauHall, signal, ideg, csum, cf, (float*)d_out);
}